// Round 1
// baseline (2784.427 us; speedup 1.0000x reference)
//
#include <hip/hip_runtime.h>
#include <math.h>

#define TOK   16384
#define HID   2048
#define INTER 8192

typedef __attribute__((ext_vector_type(8))) short short8;
typedef __attribute__((ext_vector_type(4))) float f32x4;

__device__ inline ushort f2bf(float f){
  union{float f; unsigned u;} v; v.f=f;
  unsigned r = v.u + 0x7FFFu + ((v.u>>16)&1u);
  return (ushort)(r>>16);
}
__device__ inline float bf2f(ushort u){
  union{unsigned u; float f;} v; v.u = ((unsigned)u)<<16; return v.f;
}

// ---------------- fp32 -> bf16 convert (row-major copy) ----------------
__global__ __launch_bounds__(256) void cvt_f32_bf16(const float* __restrict__ in,
                                                    ushort* __restrict__ out, int n4)
{
  int idx = blockIdx.x*blockDim.x + threadIdx.x;
  int stride = gridDim.x*blockDim.x;
  for (int i = idx; i < n4; i += stride) {
    float4 v = ((const float4*)in)[i];
    ushort4 o;
    o.x = f2bf(v.x); o.y = f2bf(v.y); o.z = f2bf(v.z); o.w = f2bf(v.w);
    ((ushort4*)out)[i] = o;
  }
}

// ---------------- transpose + convert: in[R][C] f32 -> out[C][R] bf16 ----------------
__global__ __launch_bounds__(256) void trans_cvt(const float* __restrict__ in,
                                                 ushort* __restrict__ out, int R, int C)
{
  __shared__ float t[32][33];
  int tx = threadIdx.x & 31, ty = threadIdx.x >> 5;
  int c0 = blockIdx.x*32, r0 = blockIdx.y*32;
  #pragma unroll
  for (int i = 0; i < 4; i++)
    t[ty + i*8][tx] = in[(size_t)(r0 + ty + i*8)*C + c0 + tx];
  __syncthreads();
  #pragma unroll
  for (int i = 0; i < 4; i++)
    out[(size_t)(c0 + ty + i*8)*R + r0 + tx] = f2bf(t[tx][ty + i*8]);
}

// ---------------- rank-16 contract: t[N][16] = x[N][K] @ W[K][16], fp32 x ----------------
__global__ __launch_bounds__(256) void lora_in_f32(const float* __restrict__ x,
                                                   const float* __restrict__ W,
                                                   float* __restrict__ t)
{
  int lane = threadIdx.x & 63, w = threadIdx.x >> 6;
  int row = blockIdx.x*4 + w;
  int j = lane & 15, g = lane >> 4;
  const float4* h4 = (const float4*)(x + (size_t)row*HID);
  float acc = 0.f;
  for (int kk = 0; kk < HID/16; ++kk) {
    float4 v = h4[kk*4 + g];
    int kb = kk*16 + g*4;
    acc += v.x*W[(kb+0)*16+j] + v.y*W[(kb+1)*16+j]
         + v.z*W[(kb+2)*16+j] + v.w*W[(kb+3)*16+j];
  }
  acc += __shfl_xor(acc, 16);
  acc += __shfl_xor(acc, 32);
  if (g == 0) t[(size_t)row*16 + j] = acc;
}

// ---------------- rank-16 contract, bf16 x, K=INTER ----------------
__global__ __launch_bounds__(256) void lora_in_bf16(const ushort* __restrict__ x,
                                                    const float* __restrict__ W,
                                                    float* __restrict__ t)
{
  int lane = threadIdx.x & 63, w = threadIdx.x >> 6;
  int row = blockIdx.x*4 + w;
  int j = lane & 15, g = lane >> 4;
  const ushort4* h4 = (const ushort4*)(x + (size_t)row*INTER);
  float acc = 0.f;
  for (int kk = 0; kk < INTER/16; ++kk) {
    ushort4 v = h4[kk*4 + g];
    int kb = kk*16 + g*4;
    acc += bf2f(v.x)*W[(kb+0)*16+j] + bf2f(v.y)*W[(kb+1)*16+j]
         + bf2f(v.z)*W[(kb+2)*16+j] + bf2f(v.w)*W[(kb+3)*16+j];
  }
  acc += __shfl_xor(acc, 16);
  acc += __shfl_xor(acc, 32);
  if (g == 0) t[(size_t)row*16 + j] = acc;
}

// ---------------- rank-16 expand: out[N][W] = t[N][16] @ Bm[16][W] ----------------
__global__ __launch_bounds__(256) void lora_out(const float* __restrict__ t,
                                                const float* __restrict__ Bm,
                                                float* __restrict__ out, int W)
{
  __shared__ float ts[8][16];
  int tid = threadIdx.x;
  int n0 = blockIdx.y*8, i0 = blockIdx.x*1024;
  if (tid < 128) ts[tid>>4][tid&15] = t[(size_t)(n0 + (tid>>4))*16 + (tid&15)];
  __syncthreads();
  const float4* B4 = (const float4*)Bm;
  float4 breg[16];
  #pragma unroll
  for (int r = 0; r < 16; r++) breg[r] = B4[(size_t)r*(W>>2) + (i0>>2) + tid];
  #pragma unroll
  for (int n = 0; n < 8; n++) {
    float4 o; o.x = o.y = o.z = o.w = 0.f;
    #pragma unroll
    for (int r = 0; r < 16; r++) {
      float s = ts[n][r];
      o.x += s*breg[r].x; o.y += s*breg[r].y; o.z += s*breg[r].z; o.w += s*breg[r].w;
    }
    ((float4*)(out + (size_t)(n0+n)*W + i0))[tid] = o;
  }
}

// ---------------- bf16 MFMA GEMM, C = A[M][K] @ BT[N][K]^T + bias ----------------
// EPI=0: gelu(tanh) then bf16 store to outb. EPI=1: f32 store to outf.
template<int EPI>
__global__ __launch_bounds__(256)
void gemm_bt(const ushort* __restrict__ A,
             const ushort* __restrict__ BT,
             const float* __restrict__ bias,
             ushort* __restrict__ outb,
             float* __restrict__ outf,
             int M, int N, int K, int grid_n)
{
  __shared__ __align__(16) ushort As[128*64];
  __shared__ __align__(16) ushort Bs[128*64];
  const int tid  = threadIdx.x;
  const int lane = tid & 63;
  const int wid  = tid >> 6;
  const int bx = blockIdx.x % grid_n;
  const int by = blockIdx.x / grid_n;
  const int wr = wid >> 1, wc = wid & 1;
  const int l8 = lane >> 3, c8 = lane & 7;

  const ushort* ag = A  + (size_t)(by*128 + wid*32 + l8) * K + c8*8;
  const ushort* bg = BT + (size_t)(bx*128 + wid*32 + l8) * K + c8*8;
  ushort* asw = As + wid*2048;
  ushort* bsw = Bs + wid*2048;

  f32x4 acc[4][4];
  #pragma unroll
  for (int m = 0; m < 4; m++)
    #pragma unroll
    for (int n = 0; n < 4; n++) acc[m][n] = (f32x4){0.f,0.f,0.f,0.f};

  const int fr = lane & 15, fq = lane >> 4;
  const int nk = K >> 6;
  for (int kt = 0; kt < nk; ++kt) {
    __syncthreads();
    #pragma unroll
    for (int i = 0; i < 4; i++) {
      __builtin_amdgcn_global_load_lds(
          (const __attribute__((address_space(1))) void*)(ag + (size_t)i*8*K + (size_t)kt*64),
          (__attribute__((address_space(3))) void*)(asw + i*512), 16, 0, 0);
      __builtin_amdgcn_global_load_lds(
          (const __attribute__((address_space(1))) void*)(bg + (size_t)i*8*K + (size_t)kt*64),
          (__attribute__((address_space(3))) void*)(bsw + i*512), 16, 0, 0);
    }
    __syncthreads();
    #pragma unroll
    for (int kk = 0; kk < 2; kk++) {
      short8 af[4], bfr[4];
      #pragma unroll
      for (int m = 0; m < 4; m++)
        af[m] = *(const short8*)(As + (wr*64 + m*16 + fr)*64 + kk*32 + fq*8);
      #pragma unroll
      for (int n = 0; n < 4; n++)
        bfr[n] = *(const short8*)(Bs + (wc*64 + n*16 + fr)*64 + kk*32 + fq*8);
      #pragma unroll
      for (int m = 0; m < 4; m++)
        #pragma unroll
        for (int n = 0; n < 4; n++)
          acc[m][n] = __builtin_amdgcn_mfma_f32_16x16x32_bf16(af[m], bfr[n], acc[m][n], 0, 0, 0);
    }
  }

  #pragma unroll
  for (int n = 0; n < 4; n++) {
    int colg = bx*128 + wc*64 + n*16 + fr;
    float bv = bias[colg];
    #pragma unroll
    for (int m = 0; m < 4; m++) {
      int row0 = by*128 + wr*64 + m*16 + fq*4;
      #pragma unroll
      for (int r = 0; r < 4; r++) {
        float v = acc[m][n][r] + bv;
        if (EPI == 0) {
          float u = 0.7978845608028654f*(v + 0.044715f*v*v*v);
          v = 0.5f*v*(1.0f + tanhf(u));
          outb[(size_t)(row0+r)*N + colg] = f2bf(v);
        } else {
          outf[(size_t)(row0+r)*N + colg] = v;
        }
      }
    }
  }
}

extern "C" void kernel_launch(void* const* d_in, const int* in_sizes, int n_in,
                              void* d_out, int out_size, void* d_ws, size_t ws_size,
                              hipStream_t stream)
{
  const float* hid  = (const float*)d_in[0];
  const float* Wfc  = (const float*)d_in[1];
  const float* bfc  = (const float*)d_in[2];
  const float* Wpj  = (const float*)d_in[3];
  const float* bpj  = (const float*)d_in[4];
  const float* Amat = (const float*)d_in[5];
  const float* Bmat = (const float*)d_in[6];
  const float* Cmat = (const float*)d_in[7];
  const float* Dmat = (const float*)d_in[8];

  float* out = (float*)d_out;                  // [TOK][HID]
  float* ab  = out + (size_t)TOK*HID;          // [TOK][INTER]
  float* cd  = ab  + (size_t)TOK*INTER;        // [TOK][HID]

  char* ws = (char*)d_ws;
  ushort* hidb = (ushort*)ws;  ws += (size_t)TOK*HID*2;
  ushort* wfct = (ushort*)ws;  ws += (size_t)INTER*HID*2;
  ushort* wpjt = (ushort*)ws;  ws += (size_t)HID*INTER*2;
  ushort* hbf  = (ushort*)ws;  ws += (size_t)TOK*INTER*2;
  float*  tab  = (float*)ws;   ws += (size_t)TOK*16*4;
  float*  tcd  = (float*)ws;

  // independent pre-passes
  cvt_f32_bf16<<<4096, 256, 0, stream>>>(hid, hidb, TOK*HID/4);
  trans_cvt<<<dim3(INTER/32, HID/32), 256, 0, stream>>>(Wfc, wfct, HID, INTER);
  trans_cvt<<<dim3(HID/32, INTER/32), 256, 0, stream>>>(Wpj, wpjt, INTER, HID);
  lora_in_f32<<<TOK/4, 256, 0, stream>>>(hid, Amat, tab);

  // h = gelu(hidden @ W_fc + b_fc), stored bf16
  gemm_bt<0><<<(TOK/128)*(INTER/128), 256, 0, stream>>>(
      hidb, wfct, bfc, hbf, nullptr, TOK, INTER, HID, INTER/128);

  // ab_out = (hidden @ A) @ B
  lora_out<<<dim3(INTER/1024, TOK/8), 256, 0, stream>>>(tab, Bmat, ab, INTER);

  // cd_out = (h @ C) @ D
  lora_in_bf16<<<TOK/4, 256, 0, stream>>>(hbf, Cmat, tcd);
  lora_out<<<dim3(HID/1024, TOK/8), 256, 0, stream>>>(tcd, Dmat, cd, HID);

  // out = h @ W_proj + b_proj
  gemm_bt<1><<<(TOK/128)*(HID/128), 256, 0, stream>>>(
      hbf, wpjt, bpj, nullptr, out, TOK, HID, INTER, HID/128);
}

// Round 2
// 2154.190 us; speedup vs baseline: 1.2926x; 1.2926x over previous
//
#include <hip/hip_runtime.h>
#include <math.h>

#define TOK   16384
#define HID   2048
#define INTER 8192

typedef __attribute__((ext_vector_type(8))) short short8;
typedef __attribute__((ext_vector_type(4))) float f32x4;

__device__ inline ushort f2bf(float f){
  union{float f; unsigned u;} v; v.f=f;
  unsigned r = v.u + 0x7FFFu + ((v.u>>16)&1u);
  return (ushort)(r>>16);
}
__device__ inline float bf2f(ushort u){
  union{unsigned u; float f;} v; v.u = ((unsigned)u)<<16; return v.f;
}

// ---------------- fp32 -> bf16 convert (row-major copy) ----------------
__global__ __launch_bounds__(256) void cvt_f32_bf16(const float* __restrict__ in,
                                                    ushort* __restrict__ out, int n4)
{
  int idx = blockIdx.x*blockDim.x + threadIdx.x;
  int stride = gridDim.x*blockDim.x;
  for (int i = idx; i < n4; i += stride) {
    float4 v = ((const float4*)in)[i];
    ushort4 o;
    o.x = f2bf(v.x); o.y = f2bf(v.y); o.z = f2bf(v.z); o.w = f2bf(v.w);
    ((ushort4*)out)[i] = o;
  }
}

// ---------------- transpose + convert: in[R][C] f32 -> out[C][R] bf16 ----------------
__global__ __launch_bounds__(256) void trans_cvt(const float* __restrict__ in,
                                                 ushort* __restrict__ out, int R, int C)
{
  __shared__ float t[32][33];
  int tx = threadIdx.x & 31, ty = threadIdx.x >> 5;
  int c0 = blockIdx.x*32, r0 = blockIdx.y*32;
  #pragma unroll
  for (int i = 0; i < 4; i++)
    t[ty + i*8][tx] = in[(size_t)(r0 + ty + i*8)*C + c0 + tx];
  __syncthreads();
  #pragma unroll
  for (int i = 0; i < 4; i++)
    out[(size_t)(c0 + ty + i*8)*R + r0 + tx] = f2bf(t[tx][ty + i*8]);
}

// ---------------- rank-16 contract: t[N][16] = x[N][K] @ W[K][16], fp32 x ----------------
__global__ __launch_bounds__(256) void lora_in_f32(const float* __restrict__ x,
                                                   const float* __restrict__ W,
                                                   float* __restrict__ t)
{
  int lane = threadIdx.x & 63, w = threadIdx.x >> 6;
  int row = blockIdx.x*4 + w;
  int j = lane & 15, g = lane >> 4;
  const float4* h4 = (const float4*)(x + (size_t)row*HID);
  float acc = 0.f;
  for (int kk = 0; kk < HID/16; ++kk) {
    float4 v = h4[kk*4 + g];
    int kb = kk*16 + g*4;
    acc += v.x*W[(kb+0)*16+j] + v.y*W[(kb+1)*16+j]
         + v.z*W[(kb+2)*16+j] + v.w*W[(kb+3)*16+j];
  }
  acc += __shfl_xor(acc, 16);
  acc += __shfl_xor(acc, 32);
  if (g == 0) t[(size_t)row*16 + j] = acc;
}

// ---------------- rank-16 contract, bf16 x, K=INTER ----------------
__global__ __launch_bounds__(256) void lora_in_bf16(const ushort* __restrict__ x,
                                                    const float* __restrict__ W,
                                                    float* __restrict__ t)
{
  int lane = threadIdx.x & 63, w = threadIdx.x >> 6;
  int row = blockIdx.x*4 + w;
  int j = lane & 15, g = lane >> 4;
  const ushort4* h4 = (const ushort4*)(x + (size_t)row*INTER);
  float acc = 0.f;
  for (int kk = 0; kk < INTER/16; ++kk) {
    ushort4 v = h4[kk*4 + g];
    int kb = kk*16 + g*4;
    acc += bf2f(v.x)*W[(kb+0)*16+j] + bf2f(v.y)*W[(kb+1)*16+j]
         + bf2f(v.z)*W[(kb+2)*16+j] + bf2f(v.w)*W[(kb+3)*16+j];
  }
  acc += __shfl_xor(acc, 16);
  acc += __shfl_xor(acc, 32);
  if (g == 0) t[(size_t)row*16 + j] = acc;
}

// ---------------- rank-16 expand: out[N][W] = t[N][16] @ Bm[16][W] ----------------
__global__ __launch_bounds__(256) void lora_out(const float* __restrict__ t,
                                                const float* __restrict__ Bm,
                                                float* __restrict__ out, int W)
{
  __shared__ float ts[8][16];
  int tid = threadIdx.x;
  int n0 = blockIdx.y*8, i0 = blockIdx.x*1024;
  if (tid < 128) ts[tid>>4][tid&15] = t[(size_t)(n0 + (tid>>4))*16 + (tid&15)];
  __syncthreads();
  const float4* B4 = (const float4*)Bm;
  float4 breg[16];
  #pragma unroll
  for (int r = 0; r < 16; r++) breg[r] = B4[(size_t)r*(W>>2) + (i0>>2) + tid];
  #pragma unroll
  for (int n = 0; n < 8; n++) {
    float4 o; o.x = o.y = o.z = o.w = 0.f;
    #pragma unroll
    for (int r = 0; r < 16; r++) {
      float s = ts[n][r];
      o.x += s*breg[r].x; o.y += s*breg[r].y; o.z += s*breg[r].z; o.w += s*breg[r].w;
    }
    ((float4*)(out + (size_t)(n0+n)*W + i0))[tid] = o;
  }
}

// =====================================================================
// 256x256 tile bf16 MFMA GEMM, BK=32, 8 waves (2Mx4N), 4-deep LDS ring,
// counted vmcnt, XOR bank swizzle, setprio around MFMA clusters.
// C = A[M][K] @ BT[N][K]^T + bias.  EPI=0: gelu->bf16; EPI=1: f32.
// =====================================================================
template<int EPI>
__global__ __launch_bounds__(512)
void gemm_bt(const ushort* __restrict__ A,
             const ushort* __restrict__ BT,
             const float* __restrict__ bias,
             ushort* __restrict__ outb,
             float* __restrict__ outf,
             int M, int N, int K, int grid_n)
{
  // [ring buf 0..3][A=0/B=1][256 rows * 32 cols bf16]  = 128 KiB
  __shared__ __align__(16) ushort lds[4][2][8192];

  const int tid = threadIdx.x;
  const int l   = tid & 63;
  const int w   = tid >> 6;          // wave 0..7
  const int wr  = w >> 2;            // 0..1  (M half)
  const int wc  = w & 3;             // 0..3  (N quarter)

  // XCD-aware block swizzle (grid divisible by 8)
  const int nwg = gridDim.x;
  const int cpx = nwg >> 3;
  const int bid = blockIdx.x;
  const int wg  = (bid & 7) * cpx + (bid >> 3);
  const int bx  = wg % grid_n;
  const int by  = wg / grid_n;

  // ---- staging addresses (global side carries the inverse swizzle) ----
  // thread covers row = w*32 + j*16 + (l>>2), 16B chunk col16 = l&3 (physical)
  // logical col16 = (l&3) ^ ((row>>1)&3) = (l&3) ^ ((l>>3)&3)
  const int srow = w*32 + (l >> 2);
  const int scol = (((l & 3) ^ ((l >> 3) & 3)) << 3);      // element offset
  const ushort* agp = A  + (size_t)(by*256 + srow)*K + scol;
  const ushort* bgp = BT + (size_t)(bx*256 + srow)*K + scol;
  const int ldso = w*1024;                                  // ushort units, +j*512

  // ---- fragment read offsets (swizzled) ----
  const int fr  = l & 15, fq = l >> 4;
  const int swz = fq ^ ((fr >> 1) & 3);
  const int aoff = (wr*128 + fr)*32 + swz*8;                // ushort units; +m*512
  const int boff = (wc*64  + fr)*32 + swz*8;                // +n*512

  f32x4 acc[8][4];
  #pragma unroll
  for (int m = 0; m < 8; m++)
    #pragma unroll
    for (int n = 0; n < 4; n++) acc[m][n] = (f32x4){0.f,0.f,0.f,0.f};

  auto stageA = [&](int kt) {
    const int c = kt & 3;
    #pragma unroll
    for (int j = 0; j < 2; ++j)
      __builtin_amdgcn_global_load_lds(
        (const __attribute__((address_space(1))) void*)(agp + (size_t)(j*16)*K + (size_t)kt*32),
        (__attribute__((address_space(3))) void*)(&lds[c][0][ldso + j*512]), 16, 0, 0);
  };
  auto stageB = [&](int kt) {
    const int c = kt & 3;
    #pragma unroll
    for (int j = 0; j < 2; ++j)
      __builtin_amdgcn_global_load_lds(
        (const __attribute__((address_space(1))) void*)(bgp + (size_t)(j*16)*K + (size_t)kt*32),
        (__attribute__((address_space(3))) void*)(&lds[c][1][ldso + j*512]), 16, 0, 0);
  };

  const int nk = K >> 5;

  // prologue: stage K-tiles 0,1,2; wait for tile 0 (counted, not drain)
  stageA(0); stageB(0); stageA(1); stageB(1); stageA(2); stageB(2);
  asm volatile("s_waitcnt vmcnt(8)" ::: "memory");
  __builtin_amdgcn_s_barrier();
  asm volatile("" ::: "memory");

  for (int kt = 0; kt < nk; ++kt) {
    const int c = kt & 3;
    const ushort* Ab = &lds[c][0][0];
    const ushort* Bb = &lds[c][1][0];

    // ---------- phase 1: all A frags + B n0,n1 ----------
    short8 af[8], b0, b1;
    #pragma unroll
    for (int m = 0; m < 8; ++m) af[m] = *(const short8*)(Ab + aoff + m*512);
    b0 = *(const short8*)(Bb + boff);
    b1 = *(const short8*)(Bb + boff + 512);
    if (kt + 3 < nk) stageA(kt + 3);
    asm volatile("" ::: "memory");
    __builtin_amdgcn_s_barrier();
    asm volatile("s_waitcnt lgkmcnt(0)" ::: "memory");
    __builtin_amdgcn_sched_barrier(0);
    __builtin_amdgcn_s_setprio(1);
    #pragma unroll
    for (int m = 0; m < 8; ++m) {
      acc[m][0] = __builtin_amdgcn_mfma_f32_16x16x32_bf16(af[m], b0, acc[m][0], 0,0,0);
      acc[m][1] = __builtin_amdgcn_mfma_f32_16x16x32_bf16(af[m], b1, acc[m][1], 0,0,0);
    }
    __builtin_amdgcn_s_setprio(0);
    asm volatile("" ::: "memory");
    __builtin_amdgcn_s_barrier();
    asm volatile("" ::: "memory");

    // ---------- phase 2: B n2,n3 ----------
    b0 = *(const short8*)(Bb + boff + 1024);
    b1 = *(const short8*)(Bb + boff + 1536);
    if (kt + 3 < nk) stageB(kt + 3);
    asm volatile("" ::: "memory");
    __builtin_amdgcn_s_barrier();
    asm volatile("s_waitcnt lgkmcnt(0)" ::: "memory");
    __builtin_amdgcn_sched_barrier(0);
    __builtin_amdgcn_s_setprio(1);
    #pragma unroll
    for (int m = 0; m < 8; ++m) {
      acc[m][2] = __builtin_amdgcn_mfma_f32_16x16x32_bf16(af[m], b0, acc[m][2], 0,0,0);
      acc[m][3] = __builtin_amdgcn_mfma_f32_16x16x32_bf16(af[m], b1, acc[m][3], 0,0,0);
    }
    __builtin_amdgcn_s_setprio(0);

    // ---------- K-tile boundary: counted vmcnt, then barrier ----------
    if (kt < nk - 1) {
      if (kt + 3 < nk)      asm volatile("s_waitcnt vmcnt(8)" ::: "memory");
      else if (kt + 2 < nk) asm volatile("s_waitcnt vmcnt(4)" ::: "memory");
      else                  asm volatile("s_waitcnt vmcnt(0)" ::: "memory");
      __builtin_amdgcn_s_barrier();
      asm volatile("" ::: "memory");
    }
  }

  // ---------------- epilogue ----------------
  #pragma unroll
  for (int n = 0; n < 4; ++n) {
    const int colg = bx*256 + wc*64 + n*16 + fr;
    const float bv = bias[colg];
    #pragma unroll
    for (int m = 0; m < 8; ++m) {
      const int rowg = by*256 + wr*128 + m*16 + fq*4;
      #pragma unroll
      for (int j = 0; j < 4; ++j) {
        float v = acc[m][n][j] + bv;
        if (EPI == 0) {
          float u = 0.7978845608028654f*(v + 0.044715f*v*v*v);
          float e = __builtin_amdgcn_exp2f(-2.8853900817779268f*u);
          v = v * __builtin_amdgcn_rcpf(1.0f + e);
          outb[(size_t)(rowg + j)*N + colg] = f2bf(v);
        } else {
          outf[(size_t)(rowg + j)*N + colg] = v;
        }
      }
    }
  }
}

extern "C" void kernel_launch(void* const* d_in, const int* in_sizes, int n_in,
                              void* d_out, int out_size, void* d_ws, size_t ws_size,
                              hipStream_t stream)
{
  const float* hid  = (const float*)d_in[0];
  const float* Wfc  = (const float*)d_in[1];
  const float* bfc  = (const float*)d_in[2];
  const float* Wpj  = (const float*)d_in[3];
  const float* bpj  = (const float*)d_in[4];
  const float* Amat = (const float*)d_in[5];
  const float* Bmat = (const float*)d_in[6];
  const float* Cmat = (const float*)d_in[7];
  const float* Dmat = (const float*)d_in[8];

  float* out = (float*)d_out;                  // [TOK][HID]
  float* ab  = out + (size_t)TOK*HID;          // [TOK][INTER]
  float* cd  = ab  + (size_t)TOK*INTER;        // [TOK][HID]

  char* ws = (char*)d_ws;
  ushort* hidb = (ushort*)ws;  ws += (size_t)TOK*HID*2;
  ushort* wfct = (ushort*)ws;  ws += (size_t)INTER*HID*2;
  ushort* wpjt = (ushort*)ws;  ws += (size_t)HID*INTER*2;
  ushort* hbf  = (ushort*)ws;  ws += (size_t)TOK*INTER*2;
  float*  tab  = (float*)ws;   ws += (size_t)TOK*16*4;
  float*  tcd  = (float*)ws;

  // independent pre-passes
  cvt_f32_bf16<<<4096, 256, 0, stream>>>(hid, hidb, TOK*HID/4);
  trans_cvt<<<dim3(INTER/32, HID/32), 256, 0, stream>>>(Wfc, wfct, HID, INTER);
  trans_cvt<<<dim3(HID/32, INTER/32), 256, 0, stream>>>(Wpj, wpjt, INTER, HID);
  lora_in_f32<<<TOK/4, 256, 0, stream>>>(hid, Amat, tab);

  // h = gelu(hidden @ W_fc + b_fc), stored bf16
  gemm_bt<0><<<(TOK/256)*(INTER/256), 512, 0, stream>>>(
      hidb, wfct, bfc, hbf, nullptr, TOK, INTER, HID, INTER/256);

  // ab_out = (hidden @ A) @ B
  lora_out<<<dim3(INTER/1024, TOK/8), 256, 0, stream>>>(tab, Bmat, ab, INTER);

  // cd_out = (h @ C) @ D
  lora_in_bf16<<<TOK/4, 256, 0, stream>>>(hbf, Cmat, tcd);
  lora_out<<<dim3(HID/1024, TOK/8), 256, 0, stream>>>(tcd, Dmat, cd, HID);

  // out = h @ W_proj + b_proj
  gemm_bt<1><<<(TOK/256)*(HID/256), 512, 0, stream>>>(
      hbf, wpjt, bpj, nullptr, out, TOK, HID, INTER, HID/256);
}

// Round 3
// 2034.977 us; speedup vs baseline: 1.3683x; 1.0586x over previous
//
#include <hip/hip_runtime.h>
#include <math.h>

#define TOK   16384
#define HID   2048
#define INTER 8192

typedef __attribute__((ext_vector_type(8))) short short8;
typedef __attribute__((ext_vector_type(4))) float f32x4;

__device__ inline ushort f2bf(float f){
  union{float f; unsigned u;} v; v.f=f;
  unsigned r = v.u + 0x7FFFu + ((v.u>>16)&1u);
  return (ushort)(r>>16);
}
__device__ inline float bf2f(ushort u){
  union{unsigned u; float f;} v; v.u = ((unsigned)u)<<16; return v.f;
}

// ---------------- fp32 -> bf16 convert (row-major copy) ----------------
__global__ __launch_bounds__(256) void cvt_f32_bf16(const float* __restrict__ in,
                                                    ushort* __restrict__ out, int n4)
{
  int idx = blockIdx.x*blockDim.x + threadIdx.x;
  int stride = gridDim.x*blockDim.x;
  for (int i = idx; i < n4; i += stride) {
    float4 v = ((const float4*)in)[i];
    ushort4 o;
    o.x = f2bf(v.x); o.y = f2bf(v.y); o.z = f2bf(v.z); o.w = f2bf(v.w);
    ((ushort4*)out)[i] = o;
  }
}

// ---------------- transpose + convert: in[R][C] f32 -> out[C][R] bf16 ----------------
__global__ __launch_bounds__(256) void trans_cvt(const float* __restrict__ in,
                                                 ushort* __restrict__ out, int R, int C)
{
  __shared__ float t[32][33];
  int tx = threadIdx.x & 31, ty = threadIdx.x >> 5;
  int c0 = blockIdx.x*32, r0 = blockIdx.y*32;
  #pragma unroll
  for (int i = 0; i < 4; i++)
    t[ty + i*8][tx] = in[(size_t)(r0 + ty + i*8)*C + c0 + tx];
  __syncthreads();
  #pragma unroll
  for (int i = 0; i < 4; i++)
    out[(size_t)(c0 + ty + i*8)*R + r0 + tx] = f2bf(t[tx][ty + i*8]);
}

// ---------------- rank-16 contract: t[N][16] = x[N][K] @ W[K][16], fp32 x ----------------
__global__ __launch_bounds__(256) void lora_in_f32(const float* __restrict__ x,
                                                   const float* __restrict__ W,
                                                   float* __restrict__ t)
{
  int lane = threadIdx.x & 63, w = threadIdx.x >> 6;
  int row = blockIdx.x*4 + w;
  int j = lane & 15, g = lane >> 4;
  const float4* h4 = (const float4*)(x + (size_t)row*HID);
  float acc = 0.f;
  for (int kk = 0; kk < HID/16; ++kk) {
    float4 v = h4[kk*4 + g];
    int kb = kk*16 + g*4;
    acc += v.x*W[(kb+0)*16+j] + v.y*W[(kb+1)*16+j]
         + v.z*W[(kb+2)*16+j] + v.w*W[(kb+3)*16+j];
  }
  acc += __shfl_xor(acc, 16);
  acc += __shfl_xor(acc, 32);
  if (g == 0) t[(size_t)row*16 + j] = acc;
}

// ---------------- rank-16 contract, bf16 x, K=INTER ----------------
__global__ __launch_bounds__(256) void lora_in_bf16(const ushort* __restrict__ x,
                                                    const float* __restrict__ W,
                                                    float* __restrict__ t)
{
  int lane = threadIdx.x & 63, w = threadIdx.x >> 6;
  int row = blockIdx.x*4 + w;
  int j = lane & 15, g = lane >> 4;
  const ushort4* h4 = (const ushort4*)(x + (size_t)row*INTER);
  float acc = 0.f;
  for (int kk = 0; kk < INTER/16; ++kk) {
    ushort4 v = h4[kk*4 + g];
    int kb = kk*16 + g*4;
    acc += bf2f(v.x)*W[(kb+0)*16+j] + bf2f(v.y)*W[(kb+1)*16+j]
         + bf2f(v.z)*W[(kb+2)*16+j] + bf2f(v.w)*W[(kb+3)*16+j];
  }
  acc += __shfl_xor(acc, 16);
  acc += __shfl_xor(acc, 32);
  if (g == 0) t[(size_t)row*16 + j] = acc;
}

// ---------------- rank-16 expand: out[N][W] = t[N][16] @ Bm[16][W] ----------------
__global__ __launch_bounds__(256) void lora_out(const float* __restrict__ t,
                                                const float* __restrict__ Bm,
                                                float* __restrict__ out, int W)
{
  __shared__ float ts[8][16];
  int tid = threadIdx.x;
  int n0 = blockIdx.y*8, i0 = blockIdx.x*1024;
  if (tid < 128) ts[tid>>4][tid&15] = t[(size_t)(n0 + (tid>>4))*16 + (tid&15)];
  __syncthreads();
  const float4* B4 = (const float4*)Bm;
  float4 breg[16];
  #pragma unroll
  for (int r = 0; r < 16; r++) breg[r] = B4[(size_t)r*(W>>2) + (i0>>2) + tid];
  #pragma unroll
  for (int n = 0; n < 8; n++) {
    float4 o; o.x = o.y = o.z = o.w = 0.f;
    #pragma unroll
    for (int r = 0; r < 16; r++) {
      float s = ts[n][r];
      o.x += s*breg[r].x; o.y += s*breg[r].y; o.z += s*breg[r].z; o.w += s*breg[r].w;
    }
    ((float4*)(out + (size_t)(n0+n)*W + i0))[tid] = o;
  }
}

// =====================================================================
// 256x256 bf16 MFMA GEMM, BK=32, 8 waves (2Mx4N), 4-deep LDS ring,
// cross-tile ds_read-ahead (2 register fragment sets), one barrier per
// K-tile, counted vmcnt, XOR swizzle, swapped-operand vectorized stores.
// C = A[M][K] @ BT[N][K]^T + bias.  EPI=0: gelu->bf16; EPI=1: f32.
// =====================================================================
template<int EPI>
__global__ __launch_bounds__(512, 2)
void gemm_bt(const ushort* __restrict__ A,
             const ushort* __restrict__ BT,
             const float* __restrict__ bias,
             ushort* __restrict__ outb,
             float* __restrict__ outf,
             int M, int N, int K, int grid_n)
{
  __shared__ __align__(16) ushort lds[4][2][8192];   // [ring][A/B][256x32]

  const int tid = threadIdx.x;
  const int l   = tid & 63;
  const int w   = tid >> 6;
  const int wr  = w >> 2;            // 0..1
  const int wc  = w & 3;             // 0..3

  const int nwg = gridDim.x;
  const int cpx = nwg >> 3;
  const int bid = blockIdx.x;
  const int wg  = (bid & 7) * cpx + (bid >> 3);
  const int bx  = wg % grid_n;
  const int by  = wg / grid_n;

  // staging: global side carries the inverse swizzle
  const int srow = w*32 + (l >> 2);
  const int scol = (((l & 3) ^ ((l >> 3) & 3)) << 3);
  const ushort* agp = A  + (size_t)(by*256 + srow)*K + scol;
  const ushort* bgp = BT + (size_t)(bx*256 + srow)*K + scol;
  const int ldso = w*1024;

  // fragment read offsets (swizzled)
  const int fr  = l & 15, fq = l >> 4;
  const int swz = fq ^ ((fr >> 1) & 3);
  const int aoff = (wr*128 + fr)*32 + swz*8;
  const int boff = (wc*64  + fr)*32 + swz*8;

  f32x4 acc[8][4];
  #pragma unroll
  for (int m = 0; m < 8; m++)
    #pragma unroll
    for (int n = 0; n < 4; n++) acc[m][n] = (f32x4){0.f,0.f,0.f,0.f};

  auto stage = [&](int kt) {
    const int c = kt & 3;
    #pragma unroll
    for (int j = 0; j < 2; ++j)
      __builtin_amdgcn_global_load_lds(
        (const __attribute__((address_space(1))) void*)(agp + (size_t)(j*16)*K + (size_t)kt*32),
        (__attribute__((address_space(3))) void*)(&lds[c][0][ldso + j*512]), 16, 0, 0);
    #pragma unroll
    for (int j = 0; j < 2; ++j)
      __builtin_amdgcn_global_load_lds(
        (const __attribute__((address_space(1))) void*)(bgp + (size_t)(j*16)*K + (size_t)kt*32),
        (__attribute__((address_space(3))) void*)(&lds[c][1][ldso + j*512]), 16, 0, 0);
  };

  short8 a0[8], b0[4], a1[8], b1[4];

#define READS(AS, BS, c) do {                                            \
    const ushort* Ab_ = &lds[c][0][0];                                   \
    const ushort* Bb_ = &lds[c][1][0];                                   \
    _Pragma("unroll")                                                    \
    for (int m_ = 0; m_ < 8; ++m_) AS[m_] = *(const short8*)(Ab_ + aoff + m_*512); \
    _Pragma("unroll")                                                    \
    for (int n_ = 0; n_ < 4; ++n_) BS[n_] = *(const short8*)(Bb_ + boff + n_*512); \
  } while (0)

#define MFMA32(AS, BS) do {                                              \
    __builtin_amdgcn_s_setprio(1);                                       \
    _Pragma("unroll")                                                    \
    for (int m_ = 0; m_ < 8; ++m_)                                       \
      _Pragma("unroll")                                                  \
      for (int n_ = 0; n_ < 4; ++n_)                                     \
        acc[m_][n_] = __builtin_amdgcn_mfma_f32_16x16x32_bf16(BS[n_], AS[m_], acc[m_][n_], 0,0,0); \
    __builtin_amdgcn_s_setprio(0);                                       \
  } while (0)

  const int nk = K >> 5;   // nk is even (64 or 256), >= 4

  // prologue: stage tiles 0,1,2; certify 0,1 landed; read tile 0 -> set0
  stage(0); stage(1); stage(2);
  asm volatile("s_waitcnt vmcnt(4)" ::: "memory");
  __builtin_amdgcn_s_barrier();
  asm volatile("" ::: "memory");
  READS(a0, b0, 0);

  for (int kt = 0; kt < nk; kt += 2) {
    // ---- even tile kt: compute set0, read tile kt+1 -> set1 ----
    READS(a1, b1, (kt+1) & 3);
    if (kt + 3 < nk) stage(kt + 3);
    __builtin_amdgcn_sched_barrier(0);
    MFMA32(a0, b0);
    if (kt + 3 < nk) asm volatile("s_waitcnt vmcnt(4)" ::: "memory");
    else             asm volatile("s_waitcnt vmcnt(0)" ::: "memory");
    __builtin_amdgcn_s_barrier();
    asm volatile("" ::: "memory");

    // ---- odd tile kt+1: compute set1, read tile kt+2 -> set0 ----
    if (kt + 2 < nk) READS(a0, b0, (kt+2) & 3);
    if (kt + 4 < nk) stage(kt + 4);
    __builtin_amdgcn_sched_barrier(0);
    MFMA32(a1, b1);
    if (kt + 2 < nk) {
      if (kt + 4 < nk) asm volatile("s_waitcnt vmcnt(4)" ::: "memory");
      else             asm volatile("s_waitcnt vmcnt(0)" ::: "memory");
      __builtin_amdgcn_s_barrier();
      asm volatile("" ::: "memory");
    }
  }

#undef READS
#undef MFMA32

  // ---- epilogue: lane&15 = M-row, (lane>>4)*4+r = N-col -> vector stores ----
  #pragma unroll
  for (int m = 0; m < 8; ++m) {
    const int rowg = by*256 + wr*128 + m*16 + fr;
    #pragma unroll
    for (int n = 0; n < 4; ++n) {
      const int colg = bx*256 + wc*64 + n*16 + fq*4;
      const float4 bv = *(const float4*)&bias[colg];
      float v0 = acc[m][n][0] + bv.x;
      float v1 = acc[m][n][1] + bv.y;
      float v2 = acc[m][n][2] + bv.z;
      float v3 = acc[m][n][3] + bv.w;
      if (EPI == 0) {
        #define GELU(v) do { \
          float u_ = 0.7978845608028654f*((v) + 0.044715f*(v)*(v)*(v)); \
          float e_ = __builtin_amdgcn_exp2f(-2.8853900817779268f*u_);   \
          (v) = (v) * __builtin_amdgcn_rcpf(1.0f + e_); } while(0)
        GELU(v0); GELU(v1); GELU(v2); GELU(v3);
        #undef GELU
        ushort4 o; o.x = f2bf(v0); o.y = f2bf(v1); o.z = f2bf(v2); o.w = f2bf(v3);
        *(ushort4*)&outb[(size_t)rowg*N + colg] = o;
      } else {
        float4 o; o.x = v0; o.y = v1; o.z = v2; o.w = v3;
        *(float4*)&outf[(size_t)rowg*N + colg] = o;
      }
    }
  }
}

extern "C" void kernel_launch(void* const* d_in, const int* in_sizes, int n_in,
                              void* d_out, int out_size, void* d_ws, size_t ws_size,
                              hipStream_t stream)
{
  const float* hid  = (const float*)d_in[0];
  const float* Wfc  = (const float*)d_in[1];
  const float* bfc  = (const float*)d_in[2];
  const float* Wpj  = (const float*)d_in[3];
  const float* bpj  = (const float*)d_in[4];
  const float* Amat = (const float*)d_in[5];
  const float* Bmat = (const float*)d_in[6];
  const float* Cmat = (const float*)d_in[7];
  const float* Dmat = (const float*)d_in[8];

  float* out = (float*)d_out;                  // [TOK][HID]
  float* ab  = out + (size_t)TOK*HID;          // [TOK][INTER]
  float* cd  = ab  + (size_t)TOK*INTER;        // [TOK][HID]

  char* ws = (char*)d_ws;
  ushort* hidb = (ushort*)ws;  ws += (size_t)TOK*HID*2;
  ushort* wfct = (ushort*)ws;  ws += (size_t)INTER*HID*2;
  ushort* wpjt = (ushort*)ws;  ws += (size_t)HID*INTER*2;
  ushort* hbf  = (ushort*)ws;  ws += (size_t)TOK*INTER*2;
  float*  tab  = (float*)ws;   ws += (size_t)TOK*16*4;
  float*  tcd  = (float*)ws;

  // independent pre-passes
  cvt_f32_bf16<<<4096, 256, 0, stream>>>(hid, hidb, TOK*HID/4);
  trans_cvt<<<dim3(INTER/32, HID/32), 256, 0, stream>>>(Wfc, wfct, HID, INTER);
  trans_cvt<<<dim3(HID/32, INTER/32), 256, 0, stream>>>(Wpj, wpjt, INTER, HID);
  lora_in_f32<<<TOK/4, 256, 0, stream>>>(hid, Amat, tab);

  // h = gelu(hidden @ W_fc + b_fc), stored bf16
  gemm_bt<0><<<(TOK/256)*(INTER/256), 512, 0, stream>>>(
      hidb, wfct, bfc, hbf, nullptr, TOK, INTER, HID, INTER/256);

  // ab_out = (hidden @ A) @ B
  lora_out<<<dim3(INTER/1024, TOK/8), 256, 0, stream>>>(tab, Bmat, ab, INTER);

  // cd_out = (h @ C) @ D
  lora_in_bf16<<<TOK/4, 256, 0, stream>>>(hbf, Cmat, tcd);
  lora_out<<<dim3(HID/1024, TOK/8), 256, 0, stream>>>(tcd, Dmat, cd, HID);

  // out = h @ W_proj + b_proj
  gemm_bt<1><<<(TOK/256)*(HID/256), 512, 0, stream>>>(
      hbf, wpjt, bpj, nullptr, out, TOK, HID, INTER, HID/256);
}

// Round 4
// 1422.433 us; speedup vs baseline: 1.9575x; 1.4306x over previous
//
#include <hip/hip_runtime.h>
#include <math.h>

#define TOK   16384
#define HID   2048
#define INTER 8192
#define NPART 8

typedef __attribute__((ext_vector_type(8))) short short8;
typedef __attribute__((ext_vector_type(4))) float f32x4;

__device__ inline ushort f2bf(float f){
  union{float f; unsigned u;} v; v.f=f;
  unsigned r = v.u + 0x7FFFu + ((v.u>>16)&1u);
  return (ushort)(r>>16);
}

// ---------------- fp32 -> bf16 convert (row-major copy) ----------------
__global__ __launch_bounds__(256) void cvt_f32_bf16(const float* __restrict__ in,
                                                    ushort* __restrict__ out, int n4)
{
  int idx = blockIdx.x*blockDim.x + threadIdx.x;
  int stride = gridDim.x*blockDim.x;
  for (int i = idx; i < n4; i += stride) {
    float4 v = ((const float4*)in)[i];
    ushort4 o;
    o.x = f2bf(v.x); o.y = f2bf(v.y); o.z = f2bf(v.z); o.w = f2bf(v.w);
    ((ushort4*)out)[i] = o;
  }
}

// ---------------- transpose + convert: in[R][C] f32 -> out[C][R] bf16 ----------------
__global__ __launch_bounds__(256) void trans_cvt(const float* __restrict__ in,
                                                 ushort* __restrict__ out, int R, int C)
{
  __shared__ float t[32][33];
  int tx = threadIdx.x & 31, ty = threadIdx.x >> 5;
  int c0 = blockIdx.x*32, r0 = blockIdx.y*32;
  #pragma unroll
  for (int i = 0; i < 4; i++)
    t[ty + i*8][tx] = in[(size_t)(r0 + ty + i*8)*C + c0 + tx];
  __syncthreads();
  #pragma unroll
  for (int i = 0; i < 4; i++)
    out[(size_t)(c0 + ty + i*8)*R + r0 + tx] = f2bf(t[tx][ty + i*8]);
}

// ---------------- pack W[K][16] f32 -> B-fragment layout bf16 ----------------
// out[step*512 + l*8 + j] = W[step*32 + (l>>4)*8 + j][l&15]
__global__ __launch_bounds__(256) void pack_w(const float* __restrict__ W,
                                              ushort* __restrict__ out, int K)
{
  int tid = blockIdx.x*256 + threadIdx.x;           // one per (step, lane)
  int n = (K >> 5) * 64;
  if (tid >= n) return;
  int step = tid >> 6, l = tid & 63;
  int col = l & 15, kb = step*32 + ((l >> 4) << 3);
  ushort4 o0, o1;
  o0.x = f2bf(W[(size_t)(kb+0)*16 + col]);
  o0.y = f2bf(W[(size_t)(kb+1)*16 + col]);
  o0.z = f2bf(W[(size_t)(kb+2)*16 + col]);
  o0.w = f2bf(W[(size_t)(kb+3)*16 + col]);
  o1.x = f2bf(W[(size_t)(kb+4)*16 + col]);
  o1.y = f2bf(W[(size_t)(kb+5)*16 + col]);
  o1.z = f2bf(W[(size_t)(kb+6)*16 + col]);
  o1.w = f2bf(W[(size_t)(kb+7)*16 + col]);
  ((ushort4*)(out + (size_t)tid*8))[0] = o0;
  ((ushort4*)(out + (size_t)tid*8))[1] = o1;
}

// ---------------- rank-16 contract via MFMA, split-K partials ----------------
// tpart[part][M][16] += x[M][K] @ W  (W pre-packed). jobs = (M/16)*NPART waves.
__global__ __launch_bounds__(256) void lora_in_mfma(const ushort* __restrict__ x,
                                                    const ushort* __restrict__ Wpk,
                                                    float* __restrict__ tpart,
                                                    int M, int K)
{
  const int l  = threadIdx.x & 63;
  const int wv = threadIdx.x >> 6;
  const int jid = blockIdx.x*4 + wv;
  const int nt = M >> 4;                      // power of 2 (1024)
  const int part = jid >> 10;                 // jid / nt
  const int tile = jid & (nt - 1);
  const int Kc = K / NPART;
  const int k0 = part * Kc;
  const int fr = l & 15, fq = l >> 4;

  const ushort* xp = x + (size_t)(tile*16 + fr)*K + k0 + fq*8;
  const ushort* wp = Wpk + (size_t)(k0 >> 5)*512 + l*8;

  f32x4 acc = (f32x4){0.f,0.f,0.f,0.f};
  const int ns = Kc >> 5;
  for (int s = 0; s < ns; ++s) {
    short8 av = *(const short8*)(xp + s*32);
    short8 bv = *(const short8*)(wp + s*512);
    acc = __builtin_amdgcn_mfma_f32_16x16x32_bf16(av, bv, acc, 0, 0, 0);
  }
  // D: col = l&15 (rank r), row = fq*4+reg (token within tile)
  float* o = tpart + ((size_t)part*M + tile*16)*16;
  #pragma unroll
  for (int r = 0; r < 4; ++r) o[(fq*4 + r)*16 + fr] = acc[r];
}

// ---------------- rank-16 expand: out[N][W] = (sum_p tpart[p]) @ Bm[16][W] ----------------
__global__ __launch_bounds__(256) void lora_out(const float* __restrict__ tpart,
                                                const float* __restrict__ Bm,
                                                float* __restrict__ out, int W, int M)
{
  __shared__ float ts[8][16];
  int tid = threadIdx.x;
  int n0 = blockIdx.y*8, i0 = blockIdx.x*1024;
  if (tid < 128) {
    float s = 0.f;
    #pragma unroll
    for (int p = 0; p < NPART; ++p)
      s += tpart[((size_t)p*M + n0 + (tid>>4))*16 + (tid&15)];
    ts[tid>>4][tid&15] = s;
  }
  __syncthreads();
  const float4* B4 = (const float4*)Bm;
  float4 breg[16];
  #pragma unroll
  for (int r = 0; r < 16; r++) breg[r] = B4[(size_t)r*(W>>2) + (i0>>2) + tid];
  #pragma unroll
  for (int n = 0; n < 8; n++) {
    float4 o; o.x = o.y = o.z = o.w = 0.f;
    #pragma unroll
    for (int r = 0; r < 16; r++) {
      float s = ts[n][r];
      o.x += s*breg[r].x; o.y += s*breg[r].y; o.z += s*breg[r].z; o.w += s*breg[r].w;
    }
    ((float4*)(out + (size_t)(n0+n)*W + i0))[tid] = o;
  }
}

// =====================================================================
// 256x256 bf16 MFMA GEMM, BK=32, 8 waves (2Mx4N), 4-deep LDS ring,
// cross-tile ds_read-ahead (2 register fragment sets), one barrier per
// K-tile, counted vmcnt, XOR swizzle, swapped-operand vectorized stores.
// C = A[M][K] @ BT[N][K]^T + bias.  EPI=0: gelu->bf16; EPI=1: f32.
// =====================================================================
template<int EPI>
__global__ __launch_bounds__(512, 2)
void gemm_bt(const ushort* __restrict__ A,
             const ushort* __restrict__ BT,
             const float* __restrict__ bias,
             ushort* __restrict__ outb,
             float* __restrict__ outf,
             int M, int N, int K, int grid_n)
{
  __shared__ __align__(16) ushort lds[4][2][8192];   // [ring][A/B][256x32]

  const int tid = threadIdx.x;
  const int l   = tid & 63;
  const int w   = tid >> 6;
  const int wr  = w >> 2;            // 0..1
  const int wc  = w & 3;             // 0..3

  const int nwg = gridDim.x;
  const int cpx = nwg >> 3;
  const int bid = blockIdx.x;
  const int wg  = (bid & 7) * cpx + (bid >> 3);
  const int bx  = wg % grid_n;
  const int by  = wg / grid_n;

  // staging: global side carries the inverse swizzle
  const int srow = w*32 + (l >> 2);
  const int scol = (((l & 3) ^ ((l >> 3) & 3)) << 3);
  const ushort* agp = A  + (size_t)(by*256 + srow)*K + scol;
  const ushort* bgp = BT + (size_t)(bx*256 + srow)*K + scol;
  const int ldso = w*1024;

  // fragment read offsets (swizzled)
  const int fr  = l & 15, fq = l >> 4;
  const int swz = fq ^ ((fr >> 1) & 3);
  const int aoff = (wr*128 + fr)*32 + swz*8;
  const int boff = (wc*64  + fr)*32 + swz*8;

  f32x4 acc[8][4];
  #pragma unroll
  for (int m = 0; m < 8; m++)
    #pragma unroll
    for (int n = 0; n < 4; n++) acc[m][n] = (f32x4){0.f,0.f,0.f,0.f};

  auto stage = [&](int kt) {
    const int c = kt & 3;
    #pragma unroll
    for (int j = 0; j < 2; ++j)
      __builtin_amdgcn_global_load_lds(
        (const __attribute__((address_space(1))) void*)(agp + (size_t)(j*16)*K + (size_t)kt*32),
        (__attribute__((address_space(3))) void*)(&lds[c][0][ldso + j*512]), 16, 0, 0);
    #pragma unroll
    for (int j = 0; j < 2; ++j)
      __builtin_amdgcn_global_load_lds(
        (const __attribute__((address_space(1))) void*)(bgp + (size_t)(j*16)*K + (size_t)kt*32),
        (__attribute__((address_space(3))) void*)(&lds[c][1][ldso + j*512]), 16, 0, 0);
  };

  short8 a0[8], b0[4], a1[8], b1[4];

#define READS(AS, BS, c) do {                                            \
    const ushort* Ab_ = &lds[c][0][0];                                   \
    const ushort* Bb_ = &lds[c][1][0];                                   \
    _Pragma("unroll")                                                    \
    for (int m_ = 0; m_ < 8; ++m_) AS[m_] = *(const short8*)(Ab_ + aoff + m_*512); \
    _Pragma("unroll")                                                    \
    for (int n_ = 0; n_ < 4; ++n_) BS[n_] = *(const short8*)(Bb_ + boff + n_*512); \
  } while (0)

#define MFMA32(AS, BS) do {                                              \
    __builtin_amdgcn_s_setprio(1);                                       \
    _Pragma("unroll")                                                    \
    for (int m_ = 0; m_ < 8; ++m_)                                       \
      _Pragma("unroll")                                                  \
      for (int n_ = 0; n_ < 4; ++n_)                                     \
        acc[m_][n_] = __builtin_amdgcn_mfma_f32_16x16x32_bf16(BS[n_], AS[m_], acc[m_][n_], 0,0,0); \
    __builtin_amdgcn_s_setprio(0);                                       \
  } while (0)

  const int nk = K >> 5;   // even, >= 4

  // prologue: stage tiles 0,1,2; certify 0,1 landed; read tile 0 -> set0
  stage(0); stage(1); stage(2);
  asm volatile("s_waitcnt vmcnt(4)" ::: "memory");
  __builtin_amdgcn_s_barrier();
  asm volatile("" ::: "memory");
  READS(a0, b0, 0);

  for (int kt = 0; kt < nk; kt += 2) {
    // ---- even tile kt: compute set0, read tile kt+1 -> set1 ----
    READS(a1, b1, (kt+1) & 3);
    if (kt + 3 < nk) stage(kt + 3);
    __builtin_amdgcn_sched_barrier(0);
    MFMA32(a0, b0);
    if (kt + 3 < nk) asm volatile("s_waitcnt vmcnt(4)" ::: "memory");
    else             asm volatile("s_waitcnt vmcnt(0)" ::: "memory");
    __builtin_amdgcn_s_barrier();
    asm volatile("" ::: "memory");

    // ---- odd tile kt+1: compute set1, read tile kt+2 -> set0 ----
    if (kt + 2 < nk) READS(a0, b0, (kt+2) & 3);
    if (kt + 4 < nk) stage(kt + 4);
    __builtin_amdgcn_sched_barrier(0);
    MFMA32(a1, b1);
    if (kt + 2 < nk) {
      if (kt + 4 < nk) asm volatile("s_waitcnt vmcnt(4)" ::: "memory");
      else             asm volatile("s_waitcnt vmcnt(0)" ::: "memory");
      __builtin_amdgcn_s_barrier();
      asm volatile("" ::: "memory");
    }
  }

#undef READS
#undef MFMA32

  // ---- epilogue: lane&15 = M-row, (lane>>4)*4+r = N-col -> vector stores ----
  #pragma unroll
  for (int m = 0; m < 8; ++m) {
    const int rowg = by*256 + wr*128 + m*16 + fr;
    #pragma unroll
    for (int n = 0; n < 4; ++n) {
      const int colg = bx*256 + wc*64 + n*16 + fq*4;
      const float4 bv = *(const float4*)&bias[colg];
      float v0 = acc[m][n][0] + bv.x;
      float v1 = acc[m][n][1] + bv.y;
      float v2 = acc[m][n][2] + bv.z;
      float v3 = acc[m][n][3] + bv.w;
      if (EPI == 0) {
        #define GELU(v) do { \
          float u_ = 0.7978845608028654f*((v) + 0.044715f*(v)*(v)*(v)); \
          float e_ = __builtin_amdgcn_exp2f(-2.8853900817779268f*u_);   \
          (v) = (v) * __builtin_amdgcn_rcpf(1.0f + e_); } while(0)
        GELU(v0); GELU(v1); GELU(v2); GELU(v3);
        #undef GELU
        ushort4 o; o.x = f2bf(v0); o.y = f2bf(v1); o.z = f2bf(v2); o.w = f2bf(v3);
        *(ushort4*)&outb[(size_t)rowg*N + colg] = o;
      } else {
        float4 o; o.x = v0; o.y = v1; o.z = v2; o.w = v3;
        *(float4*)&outf[(size_t)rowg*N + colg] = o;
      }
    }
  }
}

extern "C" void kernel_launch(void* const* d_in, const int* in_sizes, int n_in,
                              void* d_out, int out_size, void* d_ws, size_t ws_size,
                              hipStream_t stream)
{
  const float* hid  = (const float*)d_in[0];
  const float* Wfc  = (const float*)d_in[1];
  const float* bfc  = (const float*)d_in[2];
  const float* Wpj  = (const float*)d_in[3];
  const float* bpj  = (const float*)d_in[4];
  const float* Amat = (const float*)d_in[5];
  const float* Bmat = (const float*)d_in[6];
  const float* Cmat = (const float*)d_in[7];
  const float* Dmat = (const float*)d_in[8];

  float* out = (float*)d_out;                  // [TOK][HID]
  float* ab  = out + (size_t)TOK*HID;          // [TOK][INTER]
  float* cd  = ab  + (size_t)TOK*INTER;        // [TOK][HID]

  char* ws = (char*)d_ws;
  ushort* hidb = (ushort*)ws;  ws += (size_t)TOK*HID*2;
  ushort* wfct = (ushort*)ws;  ws += (size_t)INTER*HID*2;
  ushort* wpjt = (ushort*)ws;  ws += (size_t)HID*INTER*2;
  ushort* hbf  = (ushort*)ws;  ws += (size_t)TOK*INTER*2;
  ushort* apk  = (ushort*)ws;  ws += (size_t)HID*16*2;
  ushort* cpk  = (ushort*)ws;  ws += (size_t)INTER*16*2;
  float*  tpab = (float*)ws;   ws += (size_t)NPART*TOK*16*4;
  float*  tpcd = (float*)ws;   ws += (size_t)NPART*TOK*16*4;

  // independent pre-passes
  cvt_f32_bf16<<<4096, 256, 0, stream>>>(hid, hidb, TOK*HID/4);
  trans_cvt<<<dim3(INTER/32, HID/32), 256, 0, stream>>>(Wfc, wfct, HID, INTER);
  trans_cvt<<<dim3(HID/32, INTER/32), 256, 0, stream>>>(Wpj, wpjt, INTER, HID);
  pack_w<<<((HID/32)*64 + 255)/256, 256, 0, stream>>>(Amat, apk, HID);
  pack_w<<<((INTER/32)*64 + 255)/256, 256, 0, stream>>>(Cmat, cpk, INTER);

  // t_ab partials = hidden @ A   (uses hidb, after cvt)
  lora_in_mfma<<<(TOK/16)*NPART/4, 256, 0, stream>>>(hidb, apk, tpab, TOK, HID);

  // h = gelu(hidden @ W_fc + b_fc), stored bf16
  gemm_bt<0><<<(TOK/256)*(INTER/256), 512, 0, stream>>>(
      hidb, wfct, bfc, hbf, nullptr, TOK, INTER, HID, INTER/256);

  // ab_out = (hidden @ A) @ B
  lora_out<<<dim3(INTER/1024, TOK/8), 256, 0, stream>>>(tpab, Bmat, ab, INTER, TOK);

  // cd_out = (h @ C) @ D
  lora_in_mfma<<<(TOK/16)*NPART/4, 256, 0, stream>>>(hbf, cpk, tpcd, TOK, INTER);
  lora_out<<<dim3(HID/1024, TOK/8), 256, 0, stream>>>(tpcd, Dmat, cd, HID, TOK);

  // out = h @ W_proj + b_proj
  gemm_bt<1><<<(TOK/256)*(HID/256), 512, 0, stream>>>(
      hbf, wpjt, bpj, nullptr, out, TOK, HID, INTER, HID/256);
}